// Round 13
// baseline (109.983 us; speedup 1.0000x reference)
//
#include <hip/hip_runtime.h>
#include <hip/hip_bf16.h>
#include <stdint.h>

#define B_DIM 16384
#define H_DIM 512
#define KTOT  1024   // I + H
#define NP    2048   // 4 gates * H

typedef __attribute__((ext_vector_type(8))) short short8;
typedef __attribute__((ext_vector_type(4))) float floatx4;

static __device__ __forceinline__ unsigned short f2bf(float f) {
  unsigned int u = __float_as_uint(f);
  u += 0x7fffu + ((u >> 16) & 1u);
  return (unsigned short)(u >> 16);
}

static __device__ __forceinline__ short8 cvt8(floatx4 v0, floatx4 v1) {
  short8 o;
#pragma unroll
  for (int i = 0; i < 4; ++i) {
    o[i]     = (short)f2bf(v0[i]);
    o[i + 4] = (short)f2bf(v1[i]);
  }
  return o;
}

// ---------------------------------------------------------------------------
// MERGED pack kernel. Blocks [0, 8192): A-pack; [8192, 9216): W-pack.
//
// Packed A (bf16), 16x16x32 frag-linear, BK=32 tiles:
//   u = bm*32768 + kt*1024 + wr*512 + mh*256 + m4*64 + lane   (units of 8)
//   row = bm*256 + wr*128 + mh*64 + m4*16 + (lane&15)
//   k   = kt*32 + (lane>>4)*8 + j          (k<512 -> x, else z)
// Packed B (bf16), gate-major frags, BK=32 tiles:
//   u = bn*16384 + kt*512 + wc*256 + g*64 + lane   (units of 8)
//   h = bn*32 + wc*16 + (lane&15); gate g; k = kt*32 + (lane>>4)*8 + j
// ---------------------------------------------------------------------------
__global__ __launch_bounds__(256) void pack_kernel(
    const float* __restrict__ x, const float* __restrict__ z,
    const float* __restrict__ Wi, const float* __restrict__ Wf,
    const float* __restrict__ Wc, const float* __restrict__ Wo,
    const float* __restrict__ Ui, const float* __restrict__ Uf,
    const float* __restrict__ Uc, const float* __restrict__ Uo,
    unsigned short* __restrict__ Ap, unsigned short* __restrict__ Bp) {
  int b = blockIdx.x;
  if (b < 8192) {
    int u    = b * 256 + threadIdx.x;
    int lane = u & 63;
    int m4   = (u >> 6) & 3;
    int mh   = (u >> 8) & 1;
    int wr   = (u >> 9) & 1;
    int kt   = (u >> 10) & 31;
    int bm   = u >> 15;
    int row  = bm * 256 + wr * 128 + mh * 64 + m4 * 16 + (lane & 15);
    int k    = kt * 32 + ((lane >> 4) << 3);
    const float* src = (k < 512) ? (x + (uint64_t)row * 512 + k)
                                 : (z + (uint64_t)row * 512 + (k - 512));
    floatx4 v0 = *reinterpret_cast<const floatx4*>(src);
    floatx4 v1 = *reinterpret_cast<const floatx4*>(src + 4);
    *reinterpret_cast<short8*>(Ap + (uint64_t)u * 8) = cvt8(v0, v1);
  } else {
    int u    = (b - 8192) * 256 + threadIdx.x;
    int lane = u & 63;
    int g    = (u >> 6) & 3;
    int wc   = (u >> 8) & 1;
    int kt   = (u >> 9) & 31;
    int bn   = u >> 14;
    int h    = bn * 32 + wc * 16 + (lane & 15);
    int k    = kt * 32 + ((lane >> 4) << 3);
    const float* src;
    if (k < 512) {
      const float* W = (g == 0) ? Wi : (g == 1) ? Wf : (g == 2) ? Wc : Wo;
      src = W + (uint64_t)h * 512 + k;
    } else {
      const float* U = (g == 0) ? Ui : (g == 1) ? Uf : (g == 2) ? Uc : Uo;
      src = U + (uint64_t)h * 512 + (k - 512);
    }
    floatx4 v0 = *reinterpret_cast<const floatx4*>(src);
    floatx4 v1 = *reinterpret_cast<const floatx4*>(src + 4);
    *reinterpret_cast<short8*>(Bp + (uint64_t)u * 8) = cvt8(v0, v1);
  }
}

// ---- register-direct GEMM pieces (R10 core) ----
#define LOADSET(AS, BS, PA, PB)                                             \
  _Pragma("unroll")                                                         \
  for (int g = 0; g < 4; ++g)                                               \
    BS[g] = *reinterpret_cast<const short8*>((PB) + g * 512 + lane * 8);    \
  _Pragma("unroll")                                                         \
  for (int m = 0; m < 8; ++m)                                               \
    AS[m] = *reinterpret_cast<const short8*>(                               \
        (PA) + ((m >> 2) * 2048 + (m & 3) * 512) + lane * 8);

#define COMPUTE(AS, BS)                                                     \
  __builtin_amdgcn_s_setprio(1);                                            \
  _Pragma("unroll")                                                         \
  for (int m = 0; m < 8; ++m)                                               \
    _Pragma("unroll")                                                       \
    for (int g = 0; g < 4; ++g)                                             \
      acc[m][g] = __builtin_amdgcn_mfma_f32_16x16x32_bf16(                  \
          AS[m], BS[g], acc[m][g], 0, 0, 0);                                \
  __builtin_amdgcn_s_setprio(0);

#define ZERO_ACC                                                            \
  _Pragma("unroll")                                                         \
  for (int m = 0; m < 8; ++m)                                               \
    _Pragma("unroll")                                                       \
    for (int g = 0; g < 4; ++g)                                             \
      acc[m][g] = (floatx4){0.f, 0.f, 0.f, 0.f};

#define KLOOP(PB)                                                           \
  _Pragma("unroll 1")                                                       \
  for (int kt = 0; kt < 30; kt += 2) {                                      \
    const unsigned short* pA2 = pA + (kt + 2) * 8192;                       \
    const unsigned short* pB2 = (PB) + (kt + 2) * 4096;                     \
    COMPUTE(a0, b0)                                                         \
    LOADSET(a0, b0, pA2, pB2)                                               \
    COMPUTE(a1, b1)                                                         \
    LOADSET(a1, b1, pA2 + 8192, pB2 + 4096)                                 \
  }

// fused LSTM epilogue (lane-local: acc frag index g == gate)
#define EPILOGUE(BN)                                                        \
  {                                                                         \
    int h = (BN) * 32 + wc * 16 + (lane & 15);                              \
    float vbi = b_i[h], vbf = b_f[h], vbc = b_c[h], vbo = b_o[h];           \
    int rbase = bm * 256 + wr * 128 + ((lane >> 4) << 2);                   \
    _Pragma("unroll")                                                       \
    for (int m = 0; m < 8; ++m) {                                           \
      _Pragma("unroll")                                                     \
      for (int j = 0; j < 4; ++j) {                                         \
        int r = rbase + m * 16 + j;                                         \
        float pi = acc[m][0][j] + vbi;                                      \
        float pf = acc[m][1][j] + vbf;                                      \
        float pc = acc[m][2][j] + vbc;                                      \
        float po = acc[m][3][j] + vbo;                                      \
        float gi = 1.f / (1.f + __expf(-pi));                               \
        float gf = 1.f / (1.f + __expf(-pf));                               \
        float gc = 1.f - 2.f / (__expf(2.f * pc) + 1.f);                    \
        float go = 1.f / (1.f + __expf(-po));                               \
        float zv = z[(uint64_t)r * H_DIM + h];                              \
        float cn = gf * zv + gi * gc;                                       \
        float hn = go * (1.f - 2.f / (__expf(2.f * cn) + 1.f));             \
        outH[(uint64_t)r * H_DIM + h] = hn;                                 \
        outC[(uint64_t)r * H_DIM + h] = cn;                                 \
      }                                                                     \
    }                                                                       \
  }

// ---------------------------------------------------------------------------
// GEMM M=16384 Np=2048 K=1024. Tile 256x128, 4 waves, wave = 128x64,
// acc[8][4] = 128 AGPR. Register-direct (no LDS/barriers), depth-2 reg
// double-buffer (R10 core = best of 10 structures, 79.0 us).
// NEW (R13): PERSISTENT 2-PASS. Grid = 512 = exactly 2 blocks/CU, all
// resident -> zero round-robin boundaries (was 4 rounds). Each block does
// (bm, bnBase) then (bm, bnBase+8): A panels L2-warm on pass 2, and pass-2
// prologue loads are issued BEFORE pass-1's epilogue so they hide under
// its ~96MB/grid memory phase.
// ---------------------------------------------------------------------------
__global__ __launch_bounds__(256, 2) void lstm_gemm_kernel(
    const unsigned short* __restrict__ Ap,
    const unsigned short* __restrict__ Bp,
    const float* __restrict__ z,
    const float* __restrict__ b_i, const float* __restrict__ b_f,
    const float* __restrict__ b_c, const float* __restrict__ b_o,
    float* __restrict__ out) {
  int tid  = threadIdx.x;
  int bid  = blockIdx.x;
  int sw   = (bid & 7) * 64 + (bid >> 3);  // 512 % 8 == 0 -> bijective
  int bnB  = sw & 7;     // pass0: bnB, pass1: bnB+8
  int bm   = sw >> 3;    // 64 M-tiles (256 rows)
  int lane = tid & 63;
  int wid  = tid >> 6;   // 0..3
  int wr   = wid >> 1;   // 0..1 -> 128 rows
  int wc   = wid & 1;    // 0..1 -> 16 h * 4 gates

  const unsigned short* pA  = Ap + (uint64_t)bm * (32 * 8192) + wr * 4096;
  const unsigned short* pB0 = Bp + (uint64_t)bnB * (32 * 4096) + wc * 2048;
  const unsigned short* pB1 = pB0 + (uint64_t)8 * (32 * 4096);
  float* outH = out;
  float* outC = out + (uint64_t)B_DIM * H_DIM;

  floatx4 acc[8][4];
  short8 a0[8], b0[4], a1[8], b1[4];

  // ---- pass 0 ----
  ZERO_ACC
  LOADSET(a0, b0, pA, pB0)
  LOADSET(a1, b1, pA + 8192, pB0 + 4096)
  KLOOP(pB0)
  COMPUTE(a0, b0)
  LOADSET(a0, b0, pA, pB1)            // pass-1 tile 0 (hides under epilogue)
  COMPUTE(a1, b1)
  LOADSET(a1, b1, pA + 8192, pB1 + 4096)  // pass-1 tile 1
  EPILOGUE(bnB)

  // ---- pass 1 ----
  ZERO_ACC
  KLOOP(pB1)
  COMPUTE(a0, b0)
  COMPUTE(a1, b1)
  EPILOGUE(bnB + 8)
}

extern "C" void kernel_launch(void* const* d_in, const int* in_sizes, int n_in,
                              void* d_out, int out_size, void* d_ws, size_t ws_size,
                              hipStream_t stream) {
  const float* z  = (const float*)d_in[0];
  const float* x  = (const float*)d_in[1];
  const float* Wi = (const float*)d_in[2];
  const float* Wf = (const float*)d_in[3];
  const float* Wc = (const float*)d_in[4];
  const float* Wo = (const float*)d_in[5];
  const float* bi = (const float*)d_in[6];
  const float* bf = (const float*)d_in[7];
  const float* bc = (const float*)d_in[8];
  const float* bo = (const float*)d_in[9];
  const float* Ui = (const float*)d_in[10];
  const float* Uf = (const float*)d_in[11];
  const float* Uc = (const float*)d_in[12];
  const float* Uo = (const float*)d_in[13];

  unsigned short* Ap = (unsigned short*)d_ws;                          // 32 MB
  unsigned short* Bp = (unsigned short*)((char*)d_ws
                        + (size_t)B_DIM * KTOT * sizeof(unsigned short)); // +4 MB
  float* out = (float*)d_out;

  hipLaunchKernelGGL(pack_kernel, dim3(9216), dim3(256), 0, stream,
                     x, z, Wi, Wf, Wc, Wo, Ui, Uf, Uc, Uo, Ap, Bp);
  hipLaunchKernelGGL(lstm_gemm_kernel, dim3(512), dim3(256), 0, stream,
                     Ap, Bp, z, bi, bf, bc, bo, out);
}

// Round 14
// 97.231 us; speedup vs baseline: 1.1311x; 1.1311x over previous
//
#include <hip/hip_runtime.h>
#include <hip/hip_bf16.h>
#include <stdint.h>

#define B_DIM 16384
#define H_DIM 512
#define KTOT  1024   // I + H
#define NP    2048   // 4 gates * H

typedef __attribute__((ext_vector_type(8))) short short8;
typedef __attribute__((ext_vector_type(4))) float floatx4;

static __device__ __forceinline__ unsigned short f2bf(float f) {
  unsigned int u = __float_as_uint(f);
  u += 0x7fffu + ((u >> 16) & 1u);
  return (unsigned short)(u >> 16);
}

static __device__ __forceinline__ short8 cvt8(floatx4 v0, floatx4 v1) {
  short8 o;
#pragma unroll
  for (int i = 0; i < 4; ++i) {
    o[i]     = (short)f2bf(v0[i]);
    o[i + 4] = (short)f2bf(v1[i]);
  }
  return o;
}

// ---------------------------------------------------------------------------
// MERGED pack kernel. Blocks [0, 8192): A-pack; [8192, 9216): W-pack.
// Packed A (bf16), 16x16x32 frag-linear, BK=32 tiles:
//   u = bm*32768 + kt*1024 + wr*512 + mh*256 + m4*64 + lane   (units of 8)
//   row = bm*256 + wr*128 + mh*64 + m4*16 + (lane&15)
//   k   = kt*32 + (lane>>4)*8 + j          (k<512 -> x, else z)
// Packed B (bf16), gate-major frags, BK=32 tiles:
//   u = bn*16384 + kt*512 + wc*256 + g*64 + lane   (units of 8)
//   h = bn*32 + wc*16 + (lane&15); gate g; k = kt*32 + (lane>>4)*8 + j
// ---------------------------------------------------------------------------
__global__ __launch_bounds__(256) void pack_kernel(
    const float* __restrict__ x, const float* __restrict__ z,
    const float* __restrict__ Wi, const float* __restrict__ Wf,
    const float* __restrict__ Wc, const float* __restrict__ Wo,
    const float* __restrict__ Ui, const float* __restrict__ Uf,
    const float* __restrict__ Uc, const float* __restrict__ Uo,
    unsigned short* __restrict__ Ap, unsigned short* __restrict__ Bp) {
  int b = blockIdx.x;
  if (b < 8192) {
    int u    = b * 256 + threadIdx.x;
    int lane = u & 63;
    int m4   = (u >> 6) & 3;
    int mh   = (u >> 8) & 1;
    int wr   = (u >> 9) & 1;
    int kt   = (u >> 10) & 31;
    int bm   = u >> 15;
    int row  = bm * 256 + wr * 128 + mh * 64 + m4 * 16 + (lane & 15);
    int k    = kt * 32 + ((lane >> 4) << 3);
    const float* src = (k < 512) ? (x + (uint64_t)row * 512 + k)
                                 : (z + (uint64_t)row * 512 + (k - 512));
    floatx4 v0 = *reinterpret_cast<const floatx4*>(src);
    floatx4 v1 = *reinterpret_cast<const floatx4*>(src + 4);
    *reinterpret_cast<short8*>(Ap + (uint64_t)u * 8) = cvt8(v0, v1);
  } else {
    int u    = (b - 8192) * 256 + threadIdx.x;
    int lane = u & 63;
    int g    = (u >> 6) & 3;
    int wc   = (u >> 8) & 1;
    int kt   = (u >> 9) & 31;
    int bn   = u >> 14;
    int h    = bn * 32 + wc * 16 + (lane & 15);
    int k    = kt * 32 + ((lane >> 4) << 3);
    const float* src;
    if (k < 512) {
      const float* W = (g == 0) ? Wi : (g == 1) ? Wf : (g == 2) ? Wc : Wo;
      src = W + (uint64_t)h * 512 + k;
    } else {
      const float* U = (g == 0) ? Ui : (g == 1) ? Uf : (g == 2) ? Uc : Uo;
      src = U + (uint64_t)h * 512 + (k - 512);
    }
    floatx4 v0 = *reinterpret_cast<const floatx4*>(src);
    floatx4 v1 = *reinterpret_cast<const floatx4*>(src + 4);
    *reinterpret_cast<short8*>(Bp + (uint64_t)u * 8) = cvt8(v0, v1);
  }
}

// ---- register-direct GEMM pieces (R10 verbatim) ----
#define LOADSET(AS, BS, PA, PB)                                             \
  _Pragma("unroll")                                                         \
  for (int g = 0; g < 4; ++g)                                               \
    BS[g] = *reinterpret_cast<const short8*>((PB) + g * 512 + lane * 8);    \
  _Pragma("unroll")                                                         \
  for (int m = 0; m < 8; ++m)                                               \
    AS[m] = *reinterpret_cast<const short8*>(                               \
        (PA) + ((m >> 2) * 2048 + (m & 3) * 512) + lane * 8);

#define COMPUTE(AS, BS)                                                     \
  __builtin_amdgcn_s_setprio(1);                                            \
  _Pragma("unroll")                                                         \
  for (int m = 0; m < 8; ++m)                                               \
    _Pragma("unroll")                                                       \
    for (int g = 0; g < 4; ++g)                                             \
      acc[m][g] = __builtin_amdgcn_mfma_f32_16x16x32_bf16(                  \
          AS[m], BS[g], acc[m][g], 0, 0, 0);                                \
  __builtin_amdgcn_s_setprio(0);

// ---------------------------------------------------------------------------
// GEMM M=16384 Np=2048 K=1024. Tile 256x128, 4 waves, wave = 128x64,
// acc[8][4] = 128 AGPR. Register-direct (no LDS, no barriers), depth-2
// register double-buffer. R10 structure verbatim — best of 10 structural
// variants (79.0 us GEMM). R13's cross-epilogue prefetch removed (spilled).
// ---------------------------------------------------------------------------
__global__ __launch_bounds__(256, 2) void lstm_gemm_kernel(
    const unsigned short* __restrict__ Ap,
    const unsigned short* __restrict__ Bp,
    const float* __restrict__ z,
    const float* __restrict__ b_i, const float* __restrict__ b_f,
    const float* __restrict__ b_c, const float* __restrict__ b_o,
    float* __restrict__ out) {
  int tid  = threadIdx.x;
  int bid  = blockIdx.x;
  int sw   = (bid & 7) * 128 + (bid >> 3);  // 1024 % 8 == 0 -> bijective
  int bn   = sw & 15;    // 16 N-tiles (32 h * 4 gates)
  int bm   = sw >> 4;    // 64 M-tiles (256 rows)
  int lane = tid & 63;
  int wid  = tid >> 6;   // 0..3
  int wr   = wid >> 1;   // 0..1 -> 128 rows
  int wc   = wid & 1;    // 0..1 -> 16 h * 4 gates

  floatx4 acc[8][4];
#pragma unroll
  for (int m = 0; m < 8; ++m)
#pragma unroll
    for (int g = 0; g < 4; ++g)
      acc[m][g] = (floatx4){0.f, 0.f, 0.f, 0.f};

  // wave-private panel bases (frag-linear packed global)
  const unsigned short* pA = Ap + (uint64_t)bm * (32 * 8192) + wr * 4096;
  const unsigned short* pB = Bp + (uint64_t)bn * (32 * 4096) + wc * 2048;

  short8 a0[8], b0[4], a1[8], b1[4];

  // prologue: sets for tiles 0 and 1
  LOADSET(a0, b0, pA, pB)
  LOADSET(a1, b1, pA + 8192, pB + 4096)

#pragma unroll 1
  for (int kt = 0; kt < 30; kt += 2) {
    const unsigned short* pA2 = pA + (kt + 2) * 8192;
    const unsigned short* pB2 = pB + (kt + 2) * 4096;
    COMPUTE(a0, b0)
    LOADSET(a0, b0, pA2, pB2)           // tile kt+2 into freed set0
    COMPUTE(a1, b1)
    LOADSET(a1, b1, pA2 + 8192, pB2 + 4096)  // tile kt+3 into freed set1
  }
  // tail: tiles 30, 31 already loaded
  COMPUTE(a0, b0)
  COMPUTE(a1, b1)

  // ---- fused LSTM epilogue (lane-local: acc frag index g == gate)
  int h = bn * 32 + wc * 16 + (lane & 15);
  float vbi = b_i[h], vbf = b_f[h], vbc = b_c[h], vbo = b_o[h];
  int rbase = bm * 256 + wr * 128 + ((lane >> 4) << 2);
  float* outH = out;
  float* outC = out + (uint64_t)B_DIM * H_DIM;
#pragma unroll
  for (int m = 0; m < 8; ++m) {
#pragma unroll
    for (int j = 0; j < 4; ++j) {
      int r = rbase + m * 16 + j;
      float pi = acc[m][0][j] + vbi;
      float pf = acc[m][1][j] + vbf;
      float pc = acc[m][2][j] + vbc;
      float po = acc[m][3][j] + vbo;
      float gi = 1.f / (1.f + __expf(-pi));
      float gf = 1.f / (1.f + __expf(-pf));
      float gc = 1.f - 2.f / (__expf(2.f * pc) + 1.f);  // tanh
      float go = 1.f / (1.f + __expf(-po));
      float zv = z[(uint64_t)r * H_DIM + h];
      float cn = gf * zv + gi * gc;
      float hn = go * (1.f - 2.f / (__expf(2.f * cn) + 1.f));
      outH[(uint64_t)r * H_DIM + h] = hn;
      outC[(uint64_t)r * H_DIM + h] = cn;
    }
  }
}

extern "C" void kernel_launch(void* const* d_in, const int* in_sizes, int n_in,
                              void* d_out, int out_size, void* d_ws, size_t ws_size,
                              hipStream_t stream) {
  const float* z  = (const float*)d_in[0];
  const float* x  = (const float*)d_in[1];
  const float* Wi = (const float*)d_in[2];
  const float* Wf = (const float*)d_in[3];
  const float* Wc = (const float*)d_in[4];
  const float* Wo = (const float*)d_in[5];
  const float* bi = (const float*)d_in[6];
  const float* bf = (const float*)d_in[7];
  const float* bc = (const float*)d_in[8];
  const float* bo = (const float*)d_in[9];
  const float* Ui = (const float*)d_in[10];
  const float* Uf = (const float*)d_in[11];
  const float* Uc = (const float*)d_in[12];
  const float* Uo = (const float*)d_in[13];

  unsigned short* Ap = (unsigned short*)d_ws;                          // 32 MB
  unsigned short* Bp = (unsigned short*)((char*)d_ws
                        + (size_t)B_DIM * KTOT * sizeof(unsigned short)); // +4 MB
  float* out = (float*)d_out;

  hipLaunchKernelGGL(pack_kernel, dim3(9216), dim3(256), 0, stream,
                     x, z, Wi, Wf, Wc, Wo, Ui, Uf, Uc, Uo, Ap, Bp);
  hipLaunchKernelGGL(lstm_gemm_kernel, dim3(1024), dim3(256), 0, stream,
                     Ap, Bp, z, bi, bf, bc, bo, out);
}